// Round 7
// baseline (500.039 us; speedup 1.0000x reference)
//
#include <hip/hip_runtime.h>
#include <math.h>

#define B_ 16
#define L_ 256
#define S_ 100
#define LA_ 48
#define NA_ 32
#define E_ 64
#define D_ 768
#define H_ 12
#define NHID_ 1024
#define WIDX_ 102
#define EPSF 1e-12f

typedef __attribute__((ext_vector_type(8))) short s16x8;     // 8 bf16 (4 VGPRs) - MFMA A/B frag
typedef __attribute__((ext_vector_type(4))) float f32x4;     // MFMA C/D frag

// split x into bf16 hi + bf16 lo (RTNE), x ~= hi + lo to ~2^-17 rel
__device__ __forceinline__ void split_bf16(float x, unsigned short& h, unsigned short& l) {
  unsigned u = __float_as_uint(x);
  unsigned hr = u + 0x7FFFu + ((u >> 16) & 1u);
  h = (unsigned short)(hr >> 16);
  float r = x - __uint_as_float(hr & 0xFFFF0000u);
  unsigned u2 = __float_as_uint(r);
  unsigned lr = u2 + 0x7FFFu + ((u2 >> 16) & 1u);
  l = (unsigned short)(lr >> 16);
}

// ---------------- meta: per-b sb, sls, last ----------------
__global__ void k_meta(const int* __restrict__ idxs, const int* __restrict__ blen,
                       int* __restrict__ meta) {
  int b = blockIdx.x, t = threadIdx.x;
  __shared__ int cnt;
  if (t == 0) cnt = 0;
  __syncthreads();
  if (t < WIDX_ && idxs[b * WIDX_ + t] > 0) atomicAdd(&cnt, 1);
  __syncthreads();
  if (t == 0) {
    int sb = cnt - 2;
    meta[b * 4 + 0] = sb;
    meta[b * 4 + 1] = idxs[b * WIDX_ + sb];  // sls
    meta[b * 4 + 2] = blen[b] - 1;           // last
  }
}

// ---------------- gather sent_emb (y<S) and arg_emb (y>=S) ----------------
__global__ void k_gather(const float* __restrict__ emb, const int* __restrict__ idxs,
                         const int* __restrict__ meta, float* __restrict__ sent_emb,
                         float* __restrict__ arg_emb) {
  int b = blockIdx.y, y = blockIdx.x, t = threadIdx.x;
  int sb = meta[b * 4 + 0], sls = meta[b * 4 + 1], last = meta[b * 4 + 2];
  if (y < S_) {
    int s = y;
    float* dst = sent_emb + ((size_t)b * S_ + s) * D_;
    if (s < sb) {
      const float* src = emb + ((size_t)b * L_ + idxs[b * WIDX_ + s]) * D_;
      for (int d = t; d < D_; d += 256) dst[d] = src[d];
    } else {
      for (int d = t; d < D_; d += 256) dst[d] = 0.f;
    }
  } else {
    int l = y - S_;
    int pos = sls + 1 + l;
    float* dst = arg_emb + ((size_t)b * LA_ + l) * D_;
    if (pos < last) {
      int p = pos > (L_ - 1) ? (L_ - 1) : pos;
      const float* src = emb + ((size_t)b * L_ + p) * D_;
      for (int d = t; d < D_; d += 256) dst[d] = src[d];
    } else {
      for (int d = t; d < D_; d += 256) dst[d] = 0.f;
    }
  }
}

// ---------------- trig: weighted mean over triggers ----------------
__global__ void k_trig(const float* __restrict__ sent_emb, const float* __restrict__ is_trig,
                       float* __restrict__ trig) {
  int b = blockIdx.y;
  int d = blockIdx.x * 256 + threadIdx.x;
  float acc = 0.f, den = 0.f;
  for (int s = 0; s < S_; s++) {
    float w = is_trig[b * S_ + s];
    den += w;
    if (w != 0.f) acc += w * sent_emb[((size_t)b * S_ + s) * D_ + d];
  }
  trig[b * D_ + d] = acc / den;
}

// ---------------- entity0 = ent_map^T @ sent_emb ; writes split bf16 e0, e0*trig; nonempty --
__global__ __launch_bounds__(256) void k_entity0(const float* __restrict__ sent_emb,
                                                 const float* __restrict__ ent_map,
                                                 const float* __restrict__ trig,
                                                 unsigned short* __restrict__ e0h,
                                                 unsigned short* __restrict__ e0l,
                                                 unsigned short* __restrict__ e0th,
                                                 unsigned short* __restrict__ e0tl,
                                                 float* __restrict__ ne) {
  int b = blockIdx.y, e = blockIdx.x, t = threadIdx.x;
  float a0 = 0.f, a1 = 0.f, a2 = 0.f;
  for (int s = 0; s < S_; s++) {
    float w = ent_map[((size_t)b * S_ + s) * E_ + e];
    if (w != 0.f) {
      const float* r = sent_emb + ((size_t)b * S_ + s) * D_;
      a0 += w * r[t]; a1 += w * r[t + 256]; a2 += w * r[t + 512];
    }
  }
  size_t o = ((size_t)b * E_ + e) * D_;
  const float* tr = trig + b * D_;
  unsigned short h, lo;
  split_bf16(a0, h, lo); e0h[o + t] = h; e0l[o + t] = lo;
  split_bf16(a1, h, lo); e0h[o + t + 256] = h; e0l[o + t + 256] = lo;
  split_bf16(a2, h, lo); e0h[o + t + 512] = h; e0l[o + t + 512] = lo;
  split_bf16(a0 * tr[t], h, lo); e0th[o + t] = h; e0tl[o + t] = lo;
  split_bf16(a1 * tr[t + 256], h, lo); e0th[o + t + 256] = h; e0tl[o + t + 256] = lo;
  split_bf16(a2 * tr[t + 512], h, lo); e0th[o + t + 512] = h; e0tl[o + t + 512] = lo;
  __shared__ float red[256];
  red[t] = fabsf(a0) + fabsf(a1) + fabsf(a2);
  __syncthreads();
  for (int s2 = 128; s2 > 0; s2 >>= 1) {
    if (t < s2) red[t] += red[t + s2];
    __syncthreads();
  }
  if (t == 0) ne[b * E_ + e] = (red[0] > 0.f) ? 1.f : 0.f;
}

// ---------------- generic weighted sum: O[b,x,:] = sum_y W[b, y*sy + x*sx] * V[b,y,:] ------
__global__ __launch_bounds__(256) void k_wsum(const float* __restrict__ Wm, int wstride, int sy,
                                              int sx, const float* __restrict__ Vm,
                                              float* __restrict__ Om,
                                              unsigned short* __restrict__ oh,
                                              unsigned short* __restrict__ ol, int Y) {
  int b = blockIdx.y, x = blockIdx.x, t = threadIdx.x;
  float a0 = 0.f, a1 = 0.f, a2 = 0.f;
  const float* wb = Wm + (size_t)b * wstride + (size_t)x * sx;
  const float* vb = Vm + (size_t)b * Y * D_;
  for (int y = 0; y < Y; y++) {
    float w = wb[(size_t)y * sy];
    if (w != 0.f) {
      const float* r = vb + (size_t)y * D_;
      a0 += w * r[t]; a1 += w * r[t + 256]; a2 += w * r[t + 512];
    }
  }
  size_t oidx = ((size_t)b * gridDim.x + x) * D_;
  if (Om) {
    Om[oidx + t] = a0; Om[oidx + t + 256] = a1; Om[oidx + t + 512] = a2;
  }
  if (oh) {
    unsigned short h, lo;
    split_bf16(a0, h, lo); oh[oidx + t] = h; ol[oidx + t] = lo;
    split_bf16(a1, h, lo); oh[oidx + t + 256] = h; ol[oidx + t + 256] = lo;
    split_bf16(a2, h, lo); oh[oidx + t + 512] = h; ol[oidx + t + 512] = lo;
  }
}

// ---------------- tb[b,d] = b_ta[d] + sum_k trig[b,k]*W_ta[(D+k)*D + d] ----------------
__global__ void k_tb(const float* __restrict__ trig, const float* __restrict__ W_ta,
                     const float* __restrict__ b_ta, float* __restrict__ tb) {
  int b = blockIdx.y;
  int d = blockIdx.x * 256 + threadIdx.x;
  float acc0 = b_ta[d], acc1 = 0.f, acc2 = 0.f, acc3 = 0.f;
  float acc4 = 0.f, acc5 = 0.f, acc6 = 0.f, acc7 = 0.f;
  const float* tr = trig + b * D_;
  const float* w = W_ta + (size_t)D_ * D_ + d;
  for (int k = 0; k < D_; k += 8) {
    acc0 += tr[k + 0] * w[(size_t)(k + 0) * D_];
    acc1 += tr[k + 1] * w[(size_t)(k + 1) * D_];
    acc2 += tr[k + 2] * w[(size_t)(k + 2) * D_];
    acc3 += tr[k + 3] * w[(size_t)(k + 3) * D_];
    acc4 += tr[k + 4] * w[(size_t)(k + 4) * D_];
    acc5 += tr[k + 5] * w[(size_t)(k + 5) * D_];
    acc6 += tr[k + 6] * w[(size_t)(k + 6) * D_];
    acc7 += tr[k + 7] * w[(size_t)(k + 7) * D_];
  }
  tb[b * D_ + d] = ((acc0 + acc1) + (acc2 + acc3)) + ((acc4 + acc5) + (acc6 + acc7));
}

// ---------------- transpose + bf16-split weights: src[K][N] fp32 -> th/tl[N][K] ----------
__global__ __launch_bounds__(256) void k_cvtT(const float* __restrict__ src, int K, int N,
                                              unsigned short* __restrict__ th,
                                              unsigned short* __restrict__ tl) {
  __shared__ float tile[32][33];
  int k0 = blockIdx.x * 32, n0 = blockIdx.y * 32;
  int tr = threadIdx.x >> 3, c4 = (threadIdx.x & 7) * 4;
  float4 v = *(const float4*)(src + (size_t)(k0 + tr) * N + n0 + c4);
  tile[tr][c4] = v.x; tile[tr][c4 + 1] = v.y; tile[tr][c4 + 2] = v.z; tile[tr][c4 + 3] = v.w;
  __syncthreads();
  unsigned short h[4], l[4];
#pragma unroll
  for (int i = 0; i < 4; ++i) split_bf16(tile[c4 + i][tr], h[i], l[i]);
  size_t oo = (size_t)(n0 + tr) * K + k0 + c4;
  th[oo + 0] = h[0]; th[oo + 1] = h[1]; th[oo + 2] = h[2]; th[oo + 3] = h[3];
  tl[oo + 0] = l[0]; tl[oo + 1] = l[1]; tl[oo + 2] = l[2]; tl[oo + 3] = l[3];
}

// ---------------- MFMA GEMM, split-bf16 3-term, 128x128 tile, XCD-pinned, dbuf LDS -------
// 4 waves as 2x2; each wave owns 64x64 (4x4 of 16x16), 48 MFMA vs 16 ds_read_b128 per
// K-step (3:1 vs 1.5:1 of the 64x64 tile) -> halves per-output LDS traffic (the measured
// bottleneck: MfmaUtil 21%, VALUBusy 6%, conflicts 0 => LDS-pipe bound).
// LDS 64KB -> 2 blocks/CU; grid 320 (phase0) fully resident.
// phase 0 (80 segs x 4 blocks): job0 Cpe.h0(e0@Wta) 12segs, job1 Cpe.h1 12, job2 PeA.h0 16,
//   job3 PeA.h1 16, job4 PaA.h0 8, job5 PaA.h1 8, job6 P2 8.
// phase 1 (32 segs, 128 blocks): Q2 = entn@W1[4], K-split x2 (slabs combined in k_mix).
__global__ __launch_bounds__(256, 2) void k_mgemm(
    int phase,
    const unsigned short* __restrict__ e0h, const unsigned short* __restrict__ e0l,
    const unsigned short* __restrict__ e0th, const unsigned short* __restrict__ e0tl,
    const unsigned short* __restrict__ Ah2hh, const unsigned short* __restrict__ Ah2hl,
    const unsigned short* __restrict__ argmh, const unsigned short* __restrict__ argml,
    const unsigned short* __restrict__ Au2uh, const unsigned short* __restrict__ Au2ul,
    const unsigned short* __restrict__ entnh, const unsigned short* __restrict__ entnl,
    const unsigned short* __restrict__ WtaTh, const unsigned short* __restrict__ WtaTl,
    const unsigned short* __restrict__ W1Th, const unsigned short* __restrict__ W1Tl,
    float* __restrict__ Cpe, float* __restrict__ PeAp, float* __restrict__ PaAp,
    float* __restrict__ P2, float* __restrict__ Q2) {
  const size_t HPE = (size_t)B_ * E_ * NHID_;   // 1048576
  const size_t HPA = (size_t)B_ * NA_ * NHID_;  // 524288
  const size_t HH = (size_t)1024 * 768;
  int flat = blockIdx.x;
  int xcd = flat & 7;
  int i = flat >> 3;
  int by4 = i & 3;
  int seg = i >> 2;
  int job, bx, byTop = 0, akoff = 0, niter, bkoff, bstride, N;
  const unsigned short *Ah_, *Al_, *Bh_, *Bl_;
  float* C;
  if (phase == 0) {
    int gseg = xcd * 10 + seg;  // 0..79
    niter = 24;
    if (gseg < 12)      { job = 0; bx = gseg >> 1;                 byTop = (gseg & 1) * 4; }
    else if (gseg < 24) { job = 1; int r = gseg - 24 + 12; r = gseg - 12; bx = r >> 1; byTop = (r & 1) * 4; }
    else if (gseg < 40) { job = 2; int r = gseg - 24; bx = r >> 1; byTop = (r & 1) * 4; }
    else if (gseg < 56) { job = 3; int r = gseg - 40; bx = r >> 1; byTop = (r & 1) * 4; }
    else if (gseg < 64) { job = 4; bx = gseg - 56; }
    else if (gseg < 72) { job = 5; bx = gseg - 64; }
    else                { job = 6; bx = gseg - 72; }
    switch (job) {
      case 0: Ah_ = e0h;   Al_ = e0l;   Bh_ = WtaTh; Bl_ = WtaTl; bstride = 2304;
              bkoff = 0;        C = Cpe;        N = 768;  break;
      case 1: Ah_ = e0th;  Al_ = e0tl;  Bh_ = WtaTh; Bl_ = WtaTl; bstride = 2304;
              bkoff = 1536;     C = Cpe + HH;   N = 1024; N = 768; break;
      case 2: Ah_ = e0h;   Al_ = e0l;   Bh_ = W1Th;  Bl_ = W1Tl;  bstride = 4608;
              bkoff = 0;        C = PeAp;       N = 1024; break;
      case 3: Ah_ = Ah2hh; Al_ = Ah2hl; Bh_ = W1Th;  Bl_ = W1Tl;  bstride = 4608;
              bkoff = 3 * 768;  C = PeAp + HPE; N = 1024; break;
      case 4: Ah_ = argmh; Al_ = argml; Bh_ = W1Th;  Bl_ = W1Tl;  bstride = 4608;
              bkoff = 768;      C = PaAp;       N = 1024; break;
      case 5: Ah_ = Au2uh; Al_ = Au2ul; Bh_ = W1Th;  Bl_ = W1Tl;  bstride = 4608;
              bkoff = 5 * 768;  C = PaAp + HPA; N = 1024; break;
      default: Ah_ = argmh; Al_ = argml; Bh_ = W1Th; Bl_ = W1Tl;  bstride = 4608;
              bkoff = 2 * 768;  C = P2;         N = 1024; break;
    }
  } else {
    int gseg = xcd * 4 + seg;   // 0..31
    int kh = gseg & 1;
    int ck = gseg >> 1;         // 0..15
    bx = ck >> 1; byTop = (ck & 1) * 4;
    niter = 12; akoff = kh * 384;
    Ah_ = entnh; Al_ = entnl; Bh_ = W1Th; Bl_ = W1Tl; bstride = 4608;
    bkoff = 4 * 768 + kh * 384; C = Q2 + (size_t)kh * HPE; N = 1024;
  }
  int by = byTop + by4;

  // double-buffered swizzled LDS: (kgroup g, row r) at [buf][hl][r][g ^ ((r>>1)&3)]
  __shared__ unsigned short As[2][2][128][4][8];
  __shared__ unsigned short Bs[2][2][128][4][8];

  int tid = threadIdx.x;
  int srow = tid >> 2, sg = tid & 3;
  int wc = sg ^ ((srow >> 1) & 3);   // same for srow+64 ((r>>1) += 32, &3 unchanged)
  const unsigned short* aPh0 = Ah_ + (size_t)(by * 128 + srow) * 768 + akoff + sg * 8;
  const unsigned short* aPl0 = Al_ + (size_t)(by * 128 + srow) * 768 + akoff + sg * 8;
  const unsigned short* bPh0 = Bh_ + (size_t)(bx * 128 + srow) * bstride + bkoff + sg * 8;
  const unsigned short* bPl0 = Bl_ + (size_t)(bx * 128 + srow) * bstride + bkoff + sg * 8;
  const size_t aRo = (size_t)64 * 768;
  const size_t bRo = (size_t)64 * bstride;

  int lane = tid & 63, wave = tid >> 6;
  int wm = wave >> 1, wn = wave & 1;
  int fg = lane >> 4, fr = lane & 15;
  int ar0 = wm * 64 + fr;
  int bc0 = wn * 64 + fr;
  int ca = fg ^ ((ar0 >> 1) & 3);    // same for ar0+16k (bit4+ doesn't affect (r>>1)&3)
  int cb = fg ^ ((bc0 >> 1) & 3);

  f32x4 acc[4][4];
#pragma unroll
  for (int ii = 0; ii < 4; ++ii)
#pragma unroll
    for (int jj = 0; jj < 4; ++jj) acc[ii][jj] = (f32x4){0.f, 0.f, 0.f, 0.f};

  // single register set, 1-step lookahead (K-step ~1000cyc >> L2 latency)
  s16x8 rA0h = *(const s16x8*)(aPh0);
  s16x8 rA0l = *(const s16x8*)(aPl0);
  s16x8 rA1h = *(const s16x8*)(aPh0 + aRo);
  s16x8 rA1l = *(const s16x8*)(aPl0 + aRo);
  s16x8 rB0h = *(const s16x8*)(bPh0);
  s16x8 rB0l = *(const s16x8*)(bPl0);
  s16x8 rB1h = *(const s16x8*)(bPh0 + bRo);
  s16x8 rB1l = *(const s16x8*)(bPl0 + bRo);

#define WRITE_LDS(buf)                                    \
  {                                                       \
    *(s16x8*)&As[buf][0][srow][wc][0] = rA0h;             \
    *(s16x8*)&As[buf][0][srow + 64][wc][0] = rA1h;        \
    *(s16x8*)&As[buf][1][srow][wc][0] = rA0l;             \
    *(s16x8*)&As[buf][1][srow + 64][wc][0] = rA1l;        \
    *(s16x8*)&Bs[buf][0][srow][wc][0] = rB0h;             \
    *(s16x8*)&Bs[buf][0][srow + 64][wc][0] = rB1h;        \
    *(s16x8*)&Bs[buf][1][srow][wc][0] = rB0l;             \
    *(s16x8*)&Bs[buf][1][srow + 64][wc][0] = rB1l;        \
  }
#define LOAD_SET(t_)                                      \
  {                                                       \
    rA0h = *(const s16x8*)(aPh0 + (t_) * 32);             \
    rA0l = *(const s16x8*)(aPl0 + (t_) * 32);             \
    rA1h = *(const s16x8*)(aPh0 + aRo + (t_) * 32);       \
    rA1l = *(const s16x8*)(aPl0 + aRo + (t_) * 32);       \
    rB0h = *(const s16x8*)(bPh0 + (t_) * 32);             \
    rB0l = *(const s16x8*)(bPl0 + (t_) * 32);             \
    rB1h = *(const s16x8*)(bPh0 + bRo + (t_) * 32);       \
    rB1l = *(const s16x8*)(bPl0 + bRo + (t_) * 32);       \
  }

  WRITE_LDS(0);
  LOAD_SET(1);
  __syncthreads();

  for (int it = 0; it < niter; ++it) {
    int buf = it & 1;
    if (it + 1 < niter) {
      WRITE_LDS(buf ^ 1);
      if (it + 2 < niter) LOAD_SET(it + 2);
    }
    {
      s16x8 ah[4], al[4], bh[4], bl[4];
#pragma unroll
      for (int g = 0; g < 4; ++g) {
        ah[g] = *(const s16x8*)&As[buf][0][ar0 + g * 16][ca][0];
        al[g] = *(const s16x8*)&As[buf][1][ar0 + g * 16][ca][0];
        bh[g] = *(const s16x8*)&Bs[buf][0][bc0 + g * 16][cb][0];
        bl[g] = *(const s16x8*)&Bs[buf][1][bc0 + g * 16][cb][0];
      }
#pragma unroll
      for (int ii = 0; ii < 4; ++ii) {
#pragma unroll
        for (int jj = 0; jj < 4; ++jj) {
          acc[ii][jj] = __builtin_amdgcn_mfma_f32_16x16x32_bf16(ah[ii], bh[jj], acc[ii][jj], 0, 0, 0);
          acc[ii][jj] = __builtin_amdgcn_mfma_f32_16x16x32_bf16(ah[ii], bl[jj], acc[ii][jj], 0, 0, 0);
          acc[ii][jj] = __builtin_amdgcn_mfma_f32_16x16x32_bf16(al[ii], bh[jj], acc[ii][jj], 0, 0, 0);
        }
      }
    }
    __syncthreads();
  }
#undef WRITE_LDS
#undef LOAD_SET

  // epilogue: C/D layout col = lane&15, row = 4*(lane>>4) + reg [verified m89]
  int colb = bx * 128 + wn * 64 + fr;
  int rowb = by * 128 + wm * 64 + fg * 4;
#pragma unroll
  for (int ii = 0; ii < 4; ++ii) {
#pragma unroll
    for (int jj = 0; jj < 4; ++jj) {
      int col = colb + jj * 16;
#pragma unroll
      for (int r = 0; r < 4; ++r) {
        int row = rowb + ii * 16 + r;
        C[(size_t)row * N + col] = acc[ii][jj][r];
      }
    }
  }
}

// ---------------- combE: entn = (Cpe0 + Cpe1 + tb) * ne ; fp32 + split bf16 ----------------
__global__ __launch_bounds__(256) void k_combE(const float* __restrict__ Cpe,
                                               const float* __restrict__ tb,
                                               const float* __restrict__ ne,
                                               float* __restrict__ entn,
                                               unsigned short* __restrict__ entnh,
                                               unsigned short* __restrict__ entnl) {
  int t = threadIdx.x;
  int r0 = blockIdx.x * 4;
  const size_t HH = (size_t)1024 * 768;
#pragma unroll
  for (int i = 0; i < 4; ++i) {
    int row = r0 + i;
    int b = row >> 6;
    float nev = ne[row];
#pragma unroll
    for (int j = 0; j < 3; ++j) {
      int col = t + j * 256;
      size_t o = (size_t)row * D_ + col;
      float v = (Cpe[o] + Cpe[HH + o] + tb[(size_t)b * D_ + col]) * nev;
      entn[o] = v;
      unsigned short hh, ll;
      split_bf16(v, hh, ll);
      entnh[o] = hh; entnl[o] = ll;
    }
  }
}

// ---------------- score[b,e,a] = dot(entity_new[b,e], arg[b,a]) / sqrt(D) ----------------
__global__ __launch_bounds__(256) void k_score(const float* __restrict__ entn,
                                               const float* __restrict__ argm,
                                               float* __restrict__ score) {
  int b = blockIdx.y, e = blockIdx.x, t = threadIdx.x;
  __shared__ float ent[D_];
  const float* er = entn + ((size_t)b * E_ + e) * D_;
  for (int d = t; d < D_; d += 256) ent[d] = er[d];
  __syncthreads();
  int wave = t >> 6, lane = t & 63;
  const float scale = 0.03608439182435161f;  // 1/sqrt(768)
  for (int a = wave; a < NA_; a += 4) {
    const float* ar = argm + ((size_t)b * NA_ + a) * D_;
    float p = 0.f;
#pragma unroll
    for (int i = 0; i < 12; i++) {
      int d = lane + 64 * i;
      p += ent[d] * ar[d];
    }
    for (int off = 32; off > 0; off >>= 1) p += __shfl_down(p, off);
    if (lane == 0) score[((size_t)b * E_ + e) * NA_ + a] = p * scale;
  }
}

// ---------------- a2a = softmax(arg @ arg^T) ----------------
__global__ __launch_bounds__(256) void k_a2a(const float* __restrict__ argm,
                                             float* __restrict__ a2a) {
  int b = blockIdx.y, a = blockIdx.x, t = threadIdx.x;
  __shared__ float sA[D_];
  __shared__ float lg[NA_];
  const float* ar = argm + ((size_t)b * NA_ + a) * D_;
  for (int d = t; d < D_; d += 256) sA[d] = ar[d];
  __syncthreads();
  int wave = t >> 6, lane = t & 63;
  for (int a2 = wave; a2 < NA_; a2 += 4) {
    const float* br = argm + ((size_t)b * NA_ + a2) * D_;
    float p = 0.f;
#pragma unroll
    for (int i = 0; i < 12; i++) {
      int d = lane + 64 * i;
      p += sA[d] * br[d];
    }
    for (int off = 32; off > 0; off >>= 1) p += __shfl_down(p, off);
    if (lane == 0) lg[a2] = p;
  }
  __syncthreads();
  if (t < 64) {
    float v = (t < NA_) ? lg[t] : -INFINITY;
    float m = v;
    for (int mask = 16; mask > 0; mask >>= 1) m = fmaxf(m, __shfl_xor(m, mask));
    float ex = (t < NA_) ? expf(v - m) : 0.f;
    float sm = ex;
    for (int mask = 16; mask > 0; mask >>= 1) sm += __shfl_xor(sm, mask);
    if (t < NA_) a2a[((size_t)b * NA_ + a) * NA_ + t] = ex / sm;
  }
}

// ---------------- t2t: gathered, head-mean, per-att row-normalized, averaged ----------------
__global__ __launch_bounds__(128) void k_t2t(const float* __restrict__ att0,
                                             const float* __restrict__ att1,
                                             const float* __restrict__ att2,
                                             const int* __restrict__ idxs,
                                             const int* __restrict__ meta,
                                             float* __restrict__ t2t) {
  int b = blockIdx.y, s = blockIdx.x, t = threadIdx.x;
  int sb = meta[b * 4 + 0];
  float* out = t2t + ((size_t)b * S_ + s) * S_;
  if (s >= sb) {
    for (int j = t; j < S_; j += 128) out[j] = 0.f;
    return;
  }
  int Is = idxs[b * WIDX_ + s];
  int It = (t < S_) ? idxs[b * WIDX_ + t] : 0;
  __shared__ float row[256];
  __shared__ float red[128];
  const float* atts[3] = {att0, att1, att2};
  float accout = 0.f;
  for (int q = 0; q < 3; q++) {
    float r0 = 0.f, r1 = 0.f;
    const float* base = atts[q] + (((size_t)b * H_) * L_ + Is) * L_;
    for (int h = 0; h < H_; h++) {
      const float* rp = base + (size_t)h * L_ * L_;
      r0 += rp[t];
      r1 += rp[t + 128];
    }
    row[t] = r0;
    row[t + 128] = r1;
    __syncthreads();
    float v = (t < sb) ? row[It] * (1.f / 12.f) : 0.f;
    red[t] = v;
    __syncthreads();
    for (int s2 = 64; s2 > 0; s2 >>= 1) {
      if (t < s2) red[t] += red[t + s2];
      __syncthreads();
    }
    float rsum = red[0];
    __syncthreads();
    accout += v / fmaxf(rsum, EPSF) * (1.f / 3.f);
  }
  if (t < S_) out[t] = accout;
}

// ---------------- mix (norm fused): ps[e] = PeA.h0+h1 + b1 + sum_a (score[e,a]/rs_e)*P2[a]
//                  qs[a] = PaA.h0+h1 + sum_e (score[e,a]/cs_a)*(Q2.k0+Q2.k1)[e] ------------
__global__ __launch_bounds__(256) void k_mix(const float* __restrict__ PeAp,
                                             const float* __restrict__ PaAp,
                                             const float* __restrict__ P2,
                                             const float* __restrict__ Q2p,
                                             const float* __restrict__ score,
                                             const float* __restrict__ b1,
                                             float* __restrict__ ps, float* __restrict__ qs) {
  int b = blockIdx.y, x = blockIdx.x, t = threadIdx.x;
  int n0 = t * 4;
  const size_t HPE = (size_t)B_ * E_ * NHID_;
  const size_t HPA = (size_t)B_ * NA_ * NHID_;
  __shared__ float sc[E_];
  if (x < E_) {
    int e = x;
    size_t ro = ((size_t)b * E_ + e) * NHID_ + n0;
    float4 acc = *(const float4*)(PeAp + ro);
    float4 u1 = *(const float4*)(PeAp + HPE + ro);
    float4 bb = *(const float4*)(b1 + n0);
    acc.x += u1.x + bb.x; acc.y += u1.y + bb.y;
    acc.z += u1.z + bb.z; acc.w += u1.w + bb.w;
    if (t < NA_) sc[t] = score[((size_t)b * E_ + e) * NA_ + t];
    __syncthreads();
    float rs = 0.f;
    for (int a = 0; a < NA_; a++) rs += fabsf(sc[a]);
    rs = fmaxf(rs, EPSF);
    const float* pb = P2 + (size_t)b * NA_ * NHID_ + n0;
#pragma unroll 2
    for (int a = 0; a < NA_; a++) {
      float ww = sc[a] / rs;
      float4 p = *(const float4*)(pb + (size_t)a * NHID_);
      acc.x += ww * p.x; acc.y += ww * p.y; acc.z += ww * p.z; acc.w += ww * p.w;
    }
    *(float4*)(ps + ro) = acc;
  } else {
    int a = x - E_;
    size_t ro = ((size_t)b * NA_ + a) * NHID_ + n0;
    float4 acc = *(const float4*)(PaAp + ro);
    float4 u1 = *(const float4*)(PaAp + HPA + ro);
    acc.x += u1.x; acc.y += u1.y; acc.z += u1.z; acc.w += u1.w;
    if (t < E_) sc[t] = score[((size_t)b * E_ + t) * NA_ + a];
    __syncthreads();
    float cs = 0.f;
    for (int e = 0; e < E_; e++) cs += fabsf(sc[e]);
    cs = fmaxf(cs, EPSF);
    const float* qb = Q2p + (size_t)b * E_ * NHID_ + n0;
#pragma unroll 2
    for (int e = 0; e < E_; e++) {
      float ww = sc[e] / cs;
      float4 q0v = *(const float4*)(qb + (size_t)e * NHID_);
      float4 q1v = *(const float4*)(qb + HPE + (size_t)e * NHID_);
      acc.x += ww * (q0v.x + q1v.x); acc.y += ww * (q0v.y + q1v.y);
      acc.z += ww * (q0v.z + q1v.z); acc.w += ww * (q0v.w + q1v.w);
    }
    *(float4*)(qs + ro) = acc;
  }
}

// ---------------- final: out[b,e,a] = sum_n gelu(ps[e,n]+qs[a,n]) * W2[n] + b2 ------------
__global__ __launch_bounds__(256) void k_final(const float* __restrict__ ps,
                                               const float* __restrict__ qs,
                                               const float* __restrict__ W2,
                                               const float* __restrict__ b2,
                                               float* __restrict__ out) {
  int b = blockIdx.y, e = blockIdx.x, t = threadIdx.x;
  int wave = t >> 6, lane = t & 63;
  const float ks = 0.70710678118654752f;
  size_t po = ((size_t)b * E_ + e) * NHID_ + lane * 4;
  float4 p0 = *(const float4*)(ps + po);
  float4 p1 = *(const float4*)(ps + po + 256);
  float4 p2 = *(const float4*)(ps + po + 512);
  float4 p3 = *(const float4*)(ps + po + 768);
  const float* w2p = W2 + lane * 4;
  float4 w0 = *(const float4*)(w2p);
  float4 w1 = *(const float4*)(w2p + 256);
  float4 w2 = *(const float4*)(w2p + 512);
  float4 w3 = *(const float4*)(w2p + 768);
  __shared__ float outs[NA_];
#pragma unroll 2
  for (int a = wave; a < NA_; a += 4) {
    size_t qo = ((size_t)b * NA_ + a) * NHID_ + lane * 4;
    float4 q0 = *(const float4*)(qs + qo);
    float4 q1 = *(const float4*)(qs + qo + 256);
    float4 q2 = *(const float4*)(qs + qo + 512);
    float4 q3 = *(const float4*)(qs + qo + 768);
    float acc = 0.f;
#define GEL4(pp, qq, ww)                                          \
    {                                                             \
      float x0 = pp.x + qq.x, x1 = pp.y + qq.y;                   \
      float x2 = pp.z + qq.z, x3 = pp.w + qq.w;                   \
      float g0 = 0.5f * x0 * (1.f + erff(x0 * ks));               \
      float g1 = 0.5f * x1 * (1.f + erff(x1 * ks));               \
      float g2 = 0.5f * x2 * (1.f + erff(x2 * ks));               \
      float g3 = 0.5f * x3 * (1.f + erff(x3 * ks));               \
      acc += g0 * ww.x + g1 * ww.y + g2 * ww.z + g3 * ww.w;       \
    }
    GEL4(p0, q0, w0)
    GEL4(p1, q1, w1)
    GEL4(p2, q2, w2)
    GEL4(p3, q3, w3)
#undef GEL4
    acc += __shfl_xor(acc, 32);
    acc += __shfl_xor(acc, 16);
    acc += __shfl_xor(acc, 8);
    acc += __shfl_xor(acc, 4);
    acc += __shfl_xor(acc, 2);
    acc += __shfl_xor(acc, 1);
    if (lane == 0) outs[a] = acc;
  }
  __syncthreads();
  if (t < NA_) out[((size_t)b * E_ + e) * NA_ + t] = outs[t] + b2[0];
}

extern "C" void kernel_launch(void* const* d_in, const int* in_sizes, int n_in,
                              void* d_out, int out_size, void* d_ws, size_t ws_size,
                              hipStream_t stream) {
  const float* emb    = (const float*)d_in[0];
  const float* istrig = (const float*)d_in[1];
  const float* argw   = (const float*)d_in[2];
  const float* entmap = (const float*)d_in[3];
  const float* att0   = (const float*)d_in[4];
  const float* att1   = (const float*)d_in[5];
  const float* att2   = (const float*)d_in[6];
  const float* W_ta   = (const float*)d_in[7];
  const float* b_ta   = (const float*)d_in[8];
  const float* W1     = (const float*)d_in[9];
  const float* b1     = (const float*)d_in[10];
  const float* W2     = (const float*)d_in[11];
  const float* b2     = (const float*)d_in[12];
  const int*   idxs   = (const int*)d_in[13];
  const int*   blen   = (const int*)d_in[14];
  float* out = (float*)d_out;

  float* ws = (float*)d_ws;
  size_t o = 0;
  int* meta = (int*)ws; o += 256;
  float* sent_emb = ws + o; o += (size_t)B_ * S_ * D_;   // dead after phase A -> reused as ps
  float* arg_emb  = ws + o; o += (size_t)B_ * LA_ * D_;  // dead after argm  -> reused as qs
  float* trig     = ws + o; o += (size_t)B_ * D_;
  float* argm     = ws + o; o += (size_t)B_ * NA_ * D_;
  float* entn     = ws + o; o += (size_t)B_ * E_ * D_;
  float* tb       = ws + o; o += (size_t)B_ * D_;
  float* ne       = ws + o; o += (size_t)B_ * E_;
  float* score    = ws + o; o += (size_t)B_ * E_ * NA_;
  float* t2t      = ws + o; o += (size_t)B_ * S_ * S_;
  float* ah2h     = ws + o; o += (size_t)B_ * S_ * D_;
  float* a2a      = ws + o; o += (size_t)B_ * NA_ * NA_;
  float* Cpe      = ws + o; o += (size_t)2 * 1024 * 768;
  float* PeAp     = ws + o; o += (size_t)2 * B_ * E_ * NHID_;
  float* PaAp     = ws + o; o += (size_t)2 * B_ * NA_ * NHID_;
  float* P2       = ws + o; o += (size_t)B_ * NA_ * NHID_;
  float* Q2       = ws + o; o += (size_t)2 * B_ * E_ * NHID_;   // 2 K-slabs
  float* ps = sent_emb;  // 1.05M floats <= 1.23M
  float* qs = arg_emb;   // 0.52M floats <= 0.59M

  // split-bf16 region (hi/lo pairs), 16B-aligned
  o = (o + 3) & ~(size_t)3;
  unsigned short* us = (unsigned short*)(ws + o);
  size_t uo = 0;
  unsigned short* e0h   = us + uo; uo += (size_t)B_ * E_ * D_;
  unsigned short* e0l   = us + uo; uo += (size_t)B_ * E_ * D_;
  unsigned short* e0th  = us + uo; uo += (size_t)B_ * E_ * D_;
  unsigned short* e0tl  = us + uo; uo += (size_t)B_ * E_ * D_;
  unsigned short* Ah2hh = us + uo; uo += (size_t)B_ * E_ * D_;
  unsigned short* Ah2hl = us + uo; uo += (size_t)B_ * E_ * D_;
  unsigned short* argmh = us + uo; uo += (size_t)B_ * NA_ * D_;
  unsigned short* argml = us + uo; uo += (size_t)B_ * NA_ * D_;
  unsigned short* Au2uh = us + uo; uo += (size_t)B_ * NA_ * D_;
  unsigned short* Au2ul = us + uo; uo += (size_t)B_ * NA_ * D_;
  unsigned short* entnh = us + uo; uo += (size_t)B_ * E_ * D_;
  unsigned short* entnl = us + uo; uo += (size_t)B_ * E_ * D_;
  unsigned short* WtaTh = us + uo; uo += (size_t)2304 * 768;
  unsigned short* WtaTl = us + uo; uo += (size_t)2304 * 768;
  unsigned short* W1Th  = us + uo; uo += (size_t)4608 * 1024;
  unsigned short* W1Tl  = us + uo; uo += (size_t)4608 * 1024;

  // ---- phase A: gathers + weight transpose/split + everything not needing entity_new ----
  k_meta<<<B_, 128, 0, stream>>>(idxs, blen, meta);
  k_cvtT<<<dim3(2304 / 32, 768 / 32), 256, 0, stream>>>(W_ta, 2304, 768, WtaTh, WtaTl);
  k_cvtT<<<dim3(4608 / 32, 1024 / 32), 256, 0, stream>>>(W1, 4608, 1024, W1Th, W1Tl);
  k_gather<<<dim3(S_ + LA_, B_), 256, 0, stream>>>(emb, idxs, meta, sent_emb, arg_emb);
  k_trig<<<dim3(3, B_), 256, 0, stream>>>(sent_emb, istrig, trig);
  k_entity0<<<dim3(E_, B_), 256, 0, stream>>>(sent_emb, entmap, trig, e0h, e0l, e0th, e0tl, ne);
  k_wsum<<<dim3(NA_, B_), 256, 0, stream>>>(argw, LA_ * NA_, NA_, 1, arg_emb, argm, argmh,
                                            argml, LA_);
  k_tb<<<dim3(3, B_), 256, 0, stream>>>(trig, W_ta, b_ta, tb);
  k_t2t<<<dim3(S_, B_), 128, 0, stream>>>(att0, att1, att2, idxs, meta, t2t);
  k_wsum<<<dim3(S_, B_), 256, 0, stream>>>(t2t, S_ * S_, 1, S_, sent_emb, ah2h, nullptr,
                                           nullptr, S_);
  k_wsum<<<dim3(E_, B_), 256, 0, stream>>>(entmap, S_ * E_, E_, 1, ah2h, nullptr, Ah2hh,
                                           Ah2hl, S_);
  k_a2a<<<dim3(NA_, B_), 256, 0, stream>>>(argm, a2a);
  k_wsum<<<dim3(NA_, B_), 256, 0, stream>>>(a2a, NA_ * NA_, 1, NA_, argm, nullptr, Au2uh,
                                            Au2ul, NA_);

  // ---- phase B: XCD-pinned 128x128 tiles (80 segs = 320 blocks) ----
  k_mgemm<<<dim3(320), 256, 0, stream>>>(0, e0h, e0l, e0th, e0tl, Ah2hh, Ah2hl, argmh,
                                         argml, Au2uh, Au2ul, entnh, entnl, WtaTh, WtaTl,
                                         W1Th, W1Tl, Cpe, PeAp, PaAp, P2, Q2);

  // ---- combine entn halves + epilogue (tb, ne) + bf16 split ----
  k_combE<<<dim3(B_ * E_ / 4), 256, 0, stream>>>(Cpe, tb, ne, entn, entnh, entnl);

  // ---- Q2 = entn@W1[4], K-split x2 (128 blocks) ----
  k_mgemm<<<dim3(128), 256, 0, stream>>>(1, e0h, e0l, e0th, e0tl, Ah2hh, Ah2hl, argmh,
                                         argml, Au2uh, Au2ul, entnh, entnl, WtaTh, WtaTl,
                                         W1Th, W1Tl, Cpe, PeAp, PaAp, P2, Q2);

  // ---- phase C: score, then mix (L1-norm fused, Q2 slabs summed) ----
  k_score<<<dim3(E_, B_), 256, 0, stream>>>(entn, argm, score);
  k_mix<<<dim3(E_ + NA_, B_), 256, 0, stream>>>(PeAp, PaAp, P2, Q2, score, b1, ps, qs);

  // ---- final ----
  k_final<<<dim3(E_, B_), 256, 0, stream>>>(ps, qs, W2, b2, out);
}

// Round 8
// 489.839 us; speedup vs baseline: 1.0208x; 1.0208x over previous
//
#include <hip/hip_runtime.h>
#include <math.h>

#define B_ 16
#define L_ 256
#define S_ 100
#define LA_ 48
#define NA_ 32
#define E_ 64
#define D_ 768
#define H_ 12
#define NHID_ 1024
#define WIDX_ 102
#define EPSF 1e-12f

typedef __attribute__((ext_vector_type(8))) short s16x8;     // 8 bf16 (4 VGPRs) - MFMA A/B frag
typedef __attribute__((ext_vector_type(4))) float f32x4;     // MFMA C/D frag

// split x into bf16 hi + bf16 lo (RTNE), x ~= hi + lo to ~2^-17 rel
__device__ __forceinline__ void split_bf16(float x, unsigned short& h, unsigned short& l) {
  unsigned u = __float_as_uint(x);
  unsigned hr = u + 0x7FFFu + ((u >> 16) & 1u);
  h = (unsigned short)(hr >> 16);
  float r = x - __uint_as_float(hr & 0xFFFF0000u);
  unsigned u2 = __float_as_uint(r);
  unsigned lr = u2 + 0x7FFFu + ((u2 >> 16) & 1u);
  l = (unsigned short)(lr >> 16);
}

// ---------------- meta: per-b sb, sls, last ----------------
__global__ void k_meta(const int* __restrict__ idxs, const int* __restrict__ blen,
                       int* __restrict__ meta) {
  int b = blockIdx.x, t = threadIdx.x;
  __shared__ int cnt;
  if (t == 0) cnt = 0;
  __syncthreads();
  if (t < WIDX_ && idxs[b * WIDX_ + t] > 0) atomicAdd(&cnt, 1);
  __syncthreads();
  if (t == 0) {
    int sb = cnt - 2;
    meta[b * 4 + 0] = sb;
    meta[b * 4 + 1] = idxs[b * WIDX_ + sb];  // sls
    meta[b * 4 + 2] = blen[b] - 1;           // last
  }
}

// ---------------- gather sent_emb (y<S) and arg_emb (y>=S) ----------------
__global__ void k_gather(const float* __restrict__ emb, const int* __restrict__ idxs,
                         const int* __restrict__ meta, float* __restrict__ sent_emb,
                         float* __restrict__ arg_emb) {
  int b = blockIdx.y, y = blockIdx.x, t = threadIdx.x;
  int sb = meta[b * 4 + 0], sls = meta[b * 4 + 1], last = meta[b * 4 + 2];
  if (y < S_) {
    int s = y;
    float* dst = sent_emb + ((size_t)b * S_ + s) * D_;
    if (s < sb) {
      const float* src = emb + ((size_t)b * L_ + idxs[b * WIDX_ + s]) * D_;
      for (int d = t; d < D_; d += 256) dst[d] = src[d];
    } else {
      for (int d = t; d < D_; d += 256) dst[d] = 0.f;
    }
  } else {
    int l = y - S_;
    int pos = sls + 1 + l;
    float* dst = arg_emb + ((size_t)b * LA_ + l) * D_;
    if (pos < last) {
      int p = pos > (L_ - 1) ? (L_ - 1) : pos;
      const float* src = emb + ((size_t)b * L_ + p) * D_;
      for (int d = t; d < D_; d += 256) dst[d] = src[d];
    } else {
      for (int d = t; d < D_; d += 256) dst[d] = 0.f;
    }
  }
}

// ---------------- trig: weighted mean over triggers ----------------
__global__ void k_trig(const float* __restrict__ sent_emb, const float* __restrict__ is_trig,
                       float* __restrict__ trig) {
  int b = blockIdx.y;
  int d = blockIdx.x * 256 + threadIdx.x;
  float acc = 0.f, den = 0.f;
  for (int s = 0; s < S_; s++) {
    float w = is_trig[b * S_ + s];
    den += w;
    if (w != 0.f) acc += w * sent_emb[((size_t)b * S_ + s) * D_ + d];
  }
  trig[b * D_ + d] = acc / den;
}

// ---------------- entity0 = ent_map^T @ sent_emb ; 1D b-pinned grid (flat%8 = b%8) -------
__global__ __launch_bounds__(256) void k_entity0(const float* __restrict__ sent_emb,
                                                 const float* __restrict__ ent_map,
                                                 const float* __restrict__ trig,
                                                 unsigned short* __restrict__ e0h,
                                                 unsigned short* __restrict__ e0l,
                                                 unsigned short* __restrict__ e0th,
                                                 unsigned short* __restrict__ e0tl,
                                                 float* __restrict__ ne) {
  int flat = blockIdx.x;
  int b = flat & 15, e = flat >> 4;
  int t = threadIdx.x;
  float a0 = 0.f, a1 = 0.f, a2 = 0.f;
  for (int s = 0; s < S_; s++) {
    float w = ent_map[((size_t)b * S_ + s) * E_ + e];
    if (w != 0.f) {
      const float* r = sent_emb + ((size_t)b * S_ + s) * D_;
      a0 += w * r[t]; a1 += w * r[t + 256]; a2 += w * r[t + 512];
    }
  }
  size_t o = ((size_t)b * E_ + e) * D_;
  const float* tr = trig + b * D_;
  unsigned short h, lo;
  split_bf16(a0, h, lo); e0h[o + t] = h; e0l[o + t] = lo;
  split_bf16(a1, h, lo); e0h[o + t + 256] = h; e0l[o + t + 256] = lo;
  split_bf16(a2, h, lo); e0h[o + t + 512] = h; e0l[o + t + 512] = lo;
  split_bf16(a0 * tr[t], h, lo); e0th[o + t] = h; e0tl[o + t] = lo;
  split_bf16(a1 * tr[t + 256], h, lo); e0th[o + t + 256] = h; e0tl[o + t + 256] = lo;
  split_bf16(a2 * tr[t + 512], h, lo); e0th[o + t + 512] = h; e0tl[o + t + 512] = lo;
  __shared__ float red[256];
  red[t] = fabsf(a0) + fabsf(a1) + fabsf(a2);
  __syncthreads();
  for (int s2 = 128; s2 > 0; s2 >>= 1) {
    if (t < s2) red[t] += red[t + s2];
    __syncthreads();
  }
  if (t == 0) ne[b * E_ + e] = (red[0] > 0.f) ? 1.f : 0.f;
}

// ---------------- weighted sum, 1D b-pinned: O[b,x,:] = sum_y W[b, y*sy + x*sx] V[b,y,:] --
__global__ __launch_bounds__(256) void k_wsum(const float* __restrict__ Wm, int wstride, int sy,
                                              int sx, const float* __restrict__ Vm,
                                              float* __restrict__ Om,
                                              unsigned short* __restrict__ oh,
                                              unsigned short* __restrict__ ol, int Y, int X) {
  int flat = blockIdx.x;
  int b = flat & 15, x = flat >> 4;
  int t = threadIdx.x;
  float a0 = 0.f, a1 = 0.f, a2 = 0.f;
  const float* wb = Wm + (size_t)b * wstride + (size_t)x * sx;
  const float* vb = Vm + (size_t)b * Y * D_;
  for (int y = 0; y < Y; y++) {
    float w = wb[(size_t)y * sy];
    if (w != 0.f) {
      const float* r = vb + (size_t)y * D_;
      a0 += w * r[t]; a1 += w * r[t + 256]; a2 += w * r[t + 512];
    }
  }
  size_t oidx = ((size_t)b * X + x) * D_;
  if (Om) {
    Om[oidx + t] = a0; Om[oidx + t + 256] = a1; Om[oidx + t + 512] = a2;
  }
  if (oh) {
    unsigned short h, lo;
    split_bf16(a0, h, lo); oh[oidx + t] = h; ol[oidx + t] = lo;
    split_bf16(a1, h, lo); oh[oidx + t + 256] = h; ol[oidx + t + 256] = lo;
    split_bf16(a2, h, lo); oh[oidx + t + 512] = h; ol[oidx + t + 512] = lo;
  }
}

// ---------------- eS: w2[b,e,s'] = sum_s entmap[b,s,e] * t2t[b,s,s'] (entmap ~1 nz/col) ---
__global__ __launch_bounds__(128) void k_eS(const float* __restrict__ ent_map,
                                            const float* __restrict__ t2t,
                                            float* __restrict__ w2) {
  int flat = blockIdx.x;
  int b = flat & 15, e = flat >> 4;
  int t = threadIdx.x;
  float acc = 0.f;
  for (int s = 0; s < S_; s++) {
    float w = ent_map[((size_t)b * S_ + s) * E_ + e];
    if (w != 0.f && t < S_) acc += w * t2t[((size_t)b * S_ + s) * S_ + t];
  }
  if (t < S_) w2[((size_t)b * E_ + e) * S_ + t] = acc;
}

// ---------------- tb[b,d] = b_ta[d] + sum_k trig[b,k]*W_ta[(D+k)*D + d] ----------------
__global__ void k_tb(const float* __restrict__ trig, const float* __restrict__ W_ta,
                     const float* __restrict__ b_ta, float* __restrict__ tb) {
  int b = blockIdx.y;
  int d = blockIdx.x * 256 + threadIdx.x;
  float acc0 = b_ta[d], acc1 = 0.f, acc2 = 0.f, acc3 = 0.f;
  float acc4 = 0.f, acc5 = 0.f, acc6 = 0.f, acc7 = 0.f;
  const float* tr = trig + b * D_;
  const float* w = W_ta + (size_t)D_ * D_ + d;
  for (int k = 0; k < D_; k += 8) {
    acc0 += tr[k + 0] * w[(size_t)(k + 0) * D_];
    acc1 += tr[k + 1] * w[(size_t)(k + 1) * D_];
    acc2 += tr[k + 2] * w[(size_t)(k + 2) * D_];
    acc3 += tr[k + 3] * w[(size_t)(k + 3) * D_];
    acc4 += tr[k + 4] * w[(size_t)(k + 4) * D_];
    acc5 += tr[k + 5] * w[(size_t)(k + 5) * D_];
    acc6 += tr[k + 6] * w[(size_t)(k + 6) * D_];
    acc7 += tr[k + 7] * w[(size_t)(k + 7) * D_];
  }
  tb[b * D_ + d] = ((acc0 + acc1) + (acc2 + acc3)) + ((acc4 + acc5) + (acc6 + acc7));
}

// ---------------- transpose + bf16-split weights: src[K][N] fp32 -> th/tl[N][K] ----------
__global__ __launch_bounds__(256) void k_cvtT(const float* __restrict__ src, int K, int N,
                                              unsigned short* __restrict__ th,
                                              unsigned short* __restrict__ tl) {
  __shared__ float tile[32][33];
  int k0 = blockIdx.x * 32, n0 = blockIdx.y * 32;
  int tr = threadIdx.x >> 3, c4 = (threadIdx.x & 7) * 4;
  float4 v = *(const float4*)(src + (size_t)(k0 + tr) * N + n0 + c4);
  tile[tr][c4] = v.x; tile[tr][c4 + 1] = v.y; tile[tr][c4 + 2] = v.z; tile[tr][c4 + 3] = v.w;
  __syncthreads();
  unsigned short h[4], l[4];
#pragma unroll
  for (int i = 0; i < 4; ++i) split_bf16(tile[c4 + i][tr], h[i], l[i]);
  size_t oo = (size_t)(n0 + tr) * K + k0 + c4;
  th[oo + 0] = h[0]; th[oo + 1] = h[1]; th[oo + 2] = h[2]; th[oo + 3] = h[3];
  tl[oo + 0] = l[0]; tl[oo + 1] = l[1]; tl[oo + 2] = l[2]; tl[oo + 3] = l[3];
}

// ---------------- MFMA GEMM, split-bf16 3-term, XCD-pinned columns, dbuf LDS -------------
// (R6-proven 64x64-tile version, verbatim) 1D grid; xcd = flat%8; 160 gc-cols, 1280 blocks.
__global__ __launch_bounds__(256) void k_mgemm(
    int phase,
    const unsigned short* __restrict__ e0h, const unsigned short* __restrict__ e0l,
    const unsigned short* __restrict__ e0th, const unsigned short* __restrict__ e0tl,
    const unsigned short* __restrict__ Ah2hh, const unsigned short* __restrict__ Ah2hl,
    const unsigned short* __restrict__ argmh, const unsigned short* __restrict__ argml,
    const unsigned short* __restrict__ Au2uh, const unsigned short* __restrict__ Au2ul,
    const unsigned short* __restrict__ entnh, const unsigned short* __restrict__ entnl,
    const unsigned short* __restrict__ WtaTh, const unsigned short* __restrict__ WtaTl,
    const unsigned short* __restrict__ W1Th, const unsigned short* __restrict__ W1Tl,
    float* __restrict__ Cpe, float* __restrict__ PeAp, float* __restrict__ PaAp,
    float* __restrict__ P2, float* __restrict__ Q2) {
  const size_t HPE = (size_t)B_ * E_ * NHID_;   // 1048576
  const size_t HPA = (size_t)B_ * NA_ * NHID_;  // 524288
  const size_t HH = (size_t)1024 * 768;
  int flat = blockIdx.x;
  int xcd = flat & 7;
  int i = flat >> 3;
  int by8 = i & 7;
  int colIdx = i >> 3;
  int job, bx, byTop = 0;
  if (phase == 0) {
    int gc = xcd * 20 + colIdx;  // 0..159
    if (gc < 24)       { job = 0; int r = gc;       bx = r >> 1; byTop = (r & 1) << 3; }
    else if (gc < 48)  { job = 1; int r = gc - 24;  bx = r >> 1; byTop = (r & 1) << 3; }
    else if (gc < 80)  { job = 2; int r = gc - 48;  bx = r >> 1; byTop = (r & 1) << 3; }
    else if (gc < 112) { job = 3; int r = gc - 80;  bx = r >> 1; byTop = (r & 1) << 3; }
    else if (gc < 128) { job = 4; bx = gc - 112; }
    else if (gc < 144) { job = 5; bx = gc - 128; }
    else               { job = 6; bx = gc - 144; }
  } else {
    int gc = xcd * 4 + colIdx;   // 0..31
    job = 7; bx = gc >> 1; byTop = (gc & 1) << 3;
  }
  int by = byTop + by8;

  const unsigned short *Ah_, *Al_, *Bh_, *Bl_;
  float* C;
  int bstride, N, bkoff;
  switch (job) {
    case 0: Ah_ = e0h;   Al_ = e0l;   Bh_ = WtaTh; Bl_ = WtaTl; bstride = 2304;
            bkoff = 0;        C = Cpe;        N = 768;  break;
    case 1: Ah_ = e0th;  Al_ = e0tl;  Bh_ = WtaTh; Bl_ = WtaTl; bstride = 2304;
            bkoff = 1536;     C = Cpe + HH;   N = 768;  break;
    case 2: Ah_ = e0h;   Al_ = e0l;   Bh_ = W1Th;  Bl_ = W1Tl;  bstride = 4608;
            bkoff = 0;        C = PeAp;       N = 1024; break;
    case 3: Ah_ = Ah2hh; Al_ = Ah2hl; Bh_ = W1Th;  Bl_ = W1Tl;  bstride = 4608;
            bkoff = 3 * 768;  C = PeAp + HPE; N = 1024; break;
    case 4: Ah_ = argmh; Al_ = argml; Bh_ = W1Th;  Bl_ = W1Tl;  bstride = 4608;
            bkoff = 768;      C = PaAp;       N = 1024; break;
    case 5: Ah_ = Au2uh; Al_ = Au2ul; Bh_ = W1Th;  Bl_ = W1Tl;  bstride = 4608;
            bkoff = 5 * 768;  C = PaAp + HPA; N = 1024; break;
    case 6: Ah_ = argmh; Al_ = argml; Bh_ = W1Th;  Bl_ = W1Tl;  bstride = 4608;
            bkoff = 2 * 768;  C = P2;         N = 1024; break;
    default: Ah_ = entnh; Al_ = entnl; Bh_ = W1Th; Bl_ = W1Tl;  bstride = 4608;
            bkoff = 4 * 768;  C = Q2;         N = 1024; break;
  }

  // double-buffered swizzled LDS: (kgroup g, row r) at [buf][hl][r][g ^ ((r>>1)&3)]
  __shared__ unsigned short As[2][2][64][4][8];
  __shared__ unsigned short Bs[2][2][64][4][8];

  int tid = threadIdx.x;
  int srow = tid >> 2, sg = tid & 3;
  int wc = sg ^ ((srow >> 1) & 3);
  const unsigned short* aPh = Ah_ + (size_t)(by * 64 + srow) * 768 + sg * 8;
  const unsigned short* aPl = Al_ + (size_t)(by * 64 + srow) * 768 + sg * 8;
  const unsigned short* bPh = Bh_ + (size_t)(bx * 64 + srow) * bstride + bkoff + sg * 8;
  const unsigned short* bPl = Bl_ + (size_t)(bx * 64 + srow) * bstride + bkoff + sg * 8;

  int lane = tid & 63, wave = tid >> 6;
  int wm = wave >> 1, wn = wave & 1;
  int fg = lane >> 4, fr = lane & 15;
  int ar0 = wm * 32 + fr;
  int bc0 = wn * 32 + fr;
  int ca = fg ^ ((ar0 >> 1) & 3);
  int cb = fg ^ ((bc0 >> 1) & 3);

  f32x4 acc00 = {0.f, 0.f, 0.f, 0.f}, acc01 = {0.f, 0.f, 0.f, 0.f};
  f32x4 acc10 = {0.f, 0.f, 0.f, 0.f}, acc11 = {0.f, 0.f, 0.f, 0.f};

  const int niter = 24;
  // two register sets, 2-tile-deep prefetch
  s16x8 a0h = *(const s16x8*)(aPh + 0), a0l = *(const s16x8*)(aPl + 0);
  s16x8 b0h = *(const s16x8*)(bPh + 0), b0l = *(const s16x8*)(bPl + 0);
  s16x8 a1h = *(const s16x8*)(aPh + 32), a1l = *(const s16x8*)(aPl + 32);
  s16x8 b1h = *(const s16x8*)(bPh + 32), b1l = *(const s16x8*)(bPl + 32);

#define WRITE_LDS(buf, ah, al, bh, bl)              \
  {                                                 \
    *(s16x8*)&As[buf][0][srow][wc][0] = ah;         \
    *(s16x8*)&As[buf][1][srow][wc][0] = al;         \
    *(s16x8*)&Bs[buf][0][srow][wc][0] = bh;         \
    *(s16x8*)&Bs[buf][1][srow][wc][0] = bl;         \
  }
#define LOAD_SET(ah, al, bh, bl, t_)                \
  {                                                 \
    ah = *(const s16x8*)(aPh + (t_) * 32);          \
    al = *(const s16x8*)(aPl + (t_) * 32);          \
    bh = *(const s16x8*)(bPh + (t_) * 32);          \
    bl = *(const s16x8*)(bPl + (t_) * 32);          \
  }
#define READ_MFMA(buf)                                                          \
  {                                                                             \
    s16x8 xah0 = *(const s16x8*)&As[buf][0][ar0][ca][0];                        \
    s16x8 xah1 = *(const s16x8*)&As[buf][0][ar0 + 16][ca][0];                   \
    s16x8 xal0 = *(const s16x8*)&As[buf][1][ar0][ca][0];                        \
    s16x8 xal1 = *(const s16x8*)&As[buf][1][ar0 + 16][ca][0];                   \
    s16x8 xbh0 = *(const s16x8*)&Bs[buf][0][bc0][cb][0];                        \
    s16x8 xbh1 = *(const s16x8*)&Bs[buf][0][bc0 + 16][cb][0];                   \
    s16x8 xbl0 = *(const s16x8*)&Bs[buf][1][bc0][cb][0];                        \
    s16x8 xbl1 = *(const s16x8*)&Bs[buf][1][bc0 + 16][cb][0];                   \
    acc00 = __builtin_amdgcn_mfma_f32_16x16x32_bf16(xah0, xbh0, acc00, 0, 0, 0); \
    acc00 = __builtin_amdgcn_mfma_f32_16x16x32_bf16(xah0, xbl0, acc00, 0, 0, 0); \
    acc00 = __builtin_amdgcn_mfma_f32_16x16x32_bf16(xal0, xbh0, acc00, 0, 0, 0); \
    acc01 = __builtin_amdgcn_mfma_f32_16x16x32_bf16(xah0, xbh1, acc01, 0, 0, 0); \
    acc01 = __builtin_amdgcn_mfma_f32_16x16x32_bf16(xah0, xbl1, acc01, 0, 0, 0); \
    acc01 = __builtin_amdgcn_mfma_f32_16x16x32_bf16(xal0, xbh1, acc01, 0, 0, 0); \
    acc10 = __builtin_amdgcn_mfma_f32_16x16x32_bf16(xah1, xbh0, acc10, 0, 0, 0); \
    acc10 = __builtin_amdgcn_mfma_f32_16x16x32_bf16(xah1, xbl0, acc10, 0, 0, 0); \
    acc10 = __builtin_amdgcn_mfma_f32_16x16x32_bf16(xal1, xbh0, acc10, 0, 0, 0); \
    acc11 = __builtin_amdgcn_mfma_f32_16x16x32_bf16(xah1, xbh1, acc11, 0, 0, 0); \
    acc11 = __builtin_amdgcn_mfma_f32_16x16x32_bf16(xah1, xbl1, acc11, 0, 0, 0); \
    acc11 = __builtin_amdgcn_mfma_f32_16x16x32_bf16(xal1, xbh1, acc11, 0, 0, 0); \
  }

  WRITE_LDS(0, a0h, a0l, b0h, b0l);      // tile 0 -> buf0
  LOAD_SET(a0h, a0l, b0h, b0l, 2);       // set0 <- tile 2
  __syncthreads();

  for (int it = 0; it < niter; it += 2) {
    if (it + 1 < niter) {
      WRITE_LDS(1, a1h, a1l, b1h, b1l);
      if (it + 3 < niter) LOAD_SET(a1h, a1l, b1h, b1l, it + 3);
    }
    READ_MFMA(0);
    __syncthreads();
    if (it + 2 < niter) {
      WRITE_LDS(0, a0h, a0l, b0h, b0l);
      if (it + 4 < niter) LOAD_SET(a0h, a0l, b0h, b0l, it + 4);
    }
    READ_MFMA(1);
    __syncthreads();
  }
#undef WRITE_LDS
#undef LOAD_SET
#undef READ_MFMA

  // epilogue: C/D layout col = lane&15, row = 4*(lane>>4) + reg [verified m89]
  f32x4 accs[2][2] = {{acc00, acc01}, {acc10, acc11}};
  int colb = bx * 64 + wn * 32 + fr;
  int rowb = by * 64 + wm * 32 + fg * 4;
#pragma unroll
  for (int i2 = 0; i2 < 2; ++i2) {
#pragma unroll
    for (int j = 0; j < 2; ++j) {
      int col = colb + j * 16;
#pragma unroll
      for (int r = 0; r < 4; ++r) {
        int row = rowb + i2 * 16 + r;
        C[(size_t)row * N + col] = accs[i2][j][r];
      }
    }
  }
}

// ---------------- combE: entn = (Cpe0 + Cpe1 + tb) * ne ; fp32 + split bf16 ----------------
__global__ __launch_bounds__(256) void k_combE(const float* __restrict__ Cpe,
                                               const float* __restrict__ tb,
                                               const float* __restrict__ ne,
                                               float* __restrict__ entn,
                                               unsigned short* __restrict__ entnh,
                                               unsigned short* __restrict__ entnl) {
  int t = threadIdx.x;
  int r0 = blockIdx.x * 4;
  const size_t HH = (size_t)1024 * 768;
#pragma unroll
  for (int i = 0; i < 4; ++i) {
    int row = r0 + i;
    int b = row >> 6;
    float nev = ne[row];
#pragma unroll
    for (int j = 0; j < 3; ++j) {
      int col = t + j * 256;
      size_t o = (size_t)row * D_ + col;
      float v = (Cpe[o] + Cpe[HH + o] + tb[(size_t)b * D_ + col]) * nev;
      entn[o] = v;
      unsigned short hh, ll;
      split_bf16(v, hh, ll);
      entnh[o] = hh; entnl[o] = ll;
    }
  }
}

// ---------------- score[b,e,a] = dot(entity_new[b,e], arg[b,a]) / sqrt(D) ; 1D b-pinned ---
__global__ __launch_bounds__(256) void k_score(const float* __restrict__ entn,
                                               const float* __restrict__ argm,
                                               float* __restrict__ score) {
  int flat = blockIdx.x;
  int b = flat & 15, e = flat >> 4;
  int t = threadIdx.x;
  __shared__ float ent[D_];
  const float* er = entn + ((size_t)b * E_ + e) * D_;
  for (int d = t; d < D_; d += 256) ent[d] = er[d];
  __syncthreads();
  int wave = t >> 6, lane = t & 63;
  const float scale = 0.03608439182435161f;  // 1/sqrt(768)
  for (int a = wave; a < NA_; a += 4) {
    const float* ar = argm + ((size_t)b * NA_ + a) * D_;
    float p = 0.f;
#pragma unroll
    for (int i = 0; i < 12; i++) {
      int d = lane + 64 * i;
      p += ent[d] * ar[d];
    }
    for (int off = 32; off > 0; off >>= 1) p += __shfl_down(p, off);
    if (lane == 0) score[((size_t)b * E_ + e) * NA_ + a] = p * scale;
  }
}

// ---------------- a2a = softmax(arg @ arg^T) ; 1D b-pinned ----------------
__global__ __launch_bounds__(256) void k_a2a(const float* __restrict__ argm,
                                             float* __restrict__ a2a) {
  int flat = blockIdx.x;
  int b = flat & 15, a = flat >> 4;
  int t = threadIdx.x;
  __shared__ float sA[D_];
  __shared__ float lg[NA_];
  const float* ar = argm + ((size_t)b * NA_ + a) * D_;
  for (int d = t; d < D_; d += 256) sA[d] = ar[d];
  __syncthreads();
  int wave = t >> 6, lane = t & 63;
  for (int a2 = wave; a2 < NA_; a2 += 4) {
    const float* br = argm + ((size_t)b * NA_ + a2) * D_;
    float p = 0.f;
#pragma unroll
    for (int i = 0; i < 12; i++) {
      int d = lane + 64 * i;
      p += sA[d] * br[d];
    }
    for (int off = 32; off > 0; off >>= 1) p += __shfl_down(p, off);
    if (lane == 0) lg[a2] = p;
  }
  __syncthreads();
  if (t < 64) {
    float v = (t < NA_) ? lg[t] : -INFINITY;
    float m = v;
    for (int mask = 16; mask > 0; mask >>= 1) m = fmaxf(m, __shfl_xor(m, mask));
    float ex = (t < NA_) ? expf(v - m) : 0.f;
    float sm = ex;
    for (int mask = 16; mask > 0; mask >>= 1) sm += __shfl_xor(sm, mask);
    if (t < NA_) a2a[((size_t)b * NA_ + a) * NA_ + t] = ex / sm;
  }
}

// ---------------- t2t: gathered, head-mean, per-att row-normalized, averaged ----------------
__global__ __launch_bounds__(128) void k_t2t(const float* __restrict__ att0,
                                             const float* __restrict__ att1,
                                             const float* __restrict__ att2,
                                             const int* __restrict__ idxs,
                                             const int* __restrict__ meta,
                                             float* __restrict__ t2t) {
  int b = blockIdx.y, s = blockIdx.x, t = threadIdx.x;
  int sb = meta[b * 4 + 0];
  float* out = t2t + ((size_t)b * S_ + s) * S_;
  if (s >= sb) {
    for (int j = t; j < S_; j += 128) out[j] = 0.f;
    return;
  }
  int Is = idxs[b * WIDX_ + s];
  int It = (t < S_) ? idxs[b * WIDX_ + t] : 0;
  __shared__ float row[256];
  __shared__ float red[128];
  const float* atts[3] = {att0, att1, att2};
  float accout = 0.f;
  for (int q = 0; q < 3; q++) {
    float r0 = 0.f, r1 = 0.f;
    const float* base = atts[q] + (((size_t)b * H_) * L_ + Is) * L_;
    for (int h = 0; h < H_; h++) {
      const float* rp = base + (size_t)h * L_ * L_;
      r0 += rp[t];
      r1 += rp[t + 128];
    }
    row[t] = r0;
    row[t + 128] = r1;
    __syncthreads();
    float v = (t < sb) ? row[It] * (1.f / 12.f) : 0.f;
    red[t] = v;
    __syncthreads();
    for (int s2 = 64; s2 > 0; s2 >>= 1) {
      if (t < s2) red[t] += red[t + s2];
      __syncthreads();
    }
    float rsum = red[0];
    __syncthreads();
    accout += v / fmaxf(rsum, EPSF) * (1.f / 3.f);
  }
  if (t < S_) out[t] = accout;
}

// ---------------- mix (norm fused): ps[e] = PeA.h0+h1 + b1 + sum_a (score[e,a]/rs_e)*P2[a]
//                  qs[a] = PaA.h0+h1 + sum_e (score[e,a]/cs_a)*Q2[e] ----------------
__global__ __launch_bounds__(256) void k_mix(const float* __restrict__ PeAp,
                                             const float* __restrict__ PaAp,
                                             const float* __restrict__ P2,
                                             const float* __restrict__ Q2,
                                             const float* __restrict__ score,
                                             const float* __restrict__ b1,
                                             float* __restrict__ ps, float* __restrict__ qs) {
  int b = blockIdx.y, x = blockIdx.x, t = threadIdx.x;
  int n0 = t * 4;
  const size_t HPE = (size_t)B_ * E_ * NHID_;
  const size_t HPA = (size_t)B_ * NA_ * NHID_;
  __shared__ float sc[E_];
  if (x < E_) {
    int e = x;
    size_t ro = ((size_t)b * E_ + e) * NHID_ + n0;
    float4 acc = *(const float4*)(PeAp + ro);
    float4 u1 = *(const float4*)(PeAp + HPE + ro);
    float4 bb = *(const float4*)(b1 + n0);
    acc.x += u1.x + bb.x; acc.y += u1.y + bb.y;
    acc.z += u1.z + bb.z; acc.w += u1.w + bb.w;
    if (t < NA_) sc[t] = score[((size_t)b * E_ + e) * NA_ + t];
    __syncthreads();
    float rs = 0.f;
    for (int a = 0; a < NA_; a++) rs += fabsf(sc[a]);
    rs = fmaxf(rs, EPSF);
    const float* pb = P2 + (size_t)b * NA_ * NHID_ + n0;
#pragma unroll 2
    for (int a = 0; a < NA_; a++) {
      float ww = sc[a] / rs;
      float4 p = *(const float4*)(pb + (size_t)a * NHID_);
      acc.x += ww * p.x; acc.y += ww * p.y; acc.z += ww * p.z; acc.w += ww * p.w;
    }
    *(float4*)(ps + ro) = acc;
  } else {
    int a = x - E_;
    size_t ro = ((size_t)b * NA_ + a) * NHID_ + n0;
    float4 acc = *(const float4*)(PaAp + ro);
    float4 u1 = *(const float4*)(PaAp + HPA + ro);
    acc.x += u1.x; acc.y += u1.y; acc.z += u1.z; acc.w += u1.w;
    if (t < E_) sc[t] = score[((size_t)b * E_ + t) * NA_ + a];
    __syncthreads();
    float cs = 0.f;
    for (int e = 0; e < E_; e++) cs += fabsf(sc[e]);
    cs = fmaxf(cs, EPSF);
    const float* qb = Q2 + (size_t)b * E_ * NHID_ + n0;
#pragma unroll 2
    for (int e = 0; e < E_; e++) {
      float ww = sc[e] / cs;
      float4 q = *(const float4*)(qb + (size_t)e * NHID_);
      acc.x += ww * q.x; acc.y += ww * q.y; acc.z += ww * q.z; acc.w += ww * q.w;
    }
    *(float4*)(qs + ro) = acc;
  }
}

// ---------------- final: out[b,e,a] = sum_n gelu(ps[e,n]+qs[a,n]) * W2[n] + b2 ------------
__global__ __launch_bounds__(256) void k_final(const float* __restrict__ ps,
                                               const float* __restrict__ qs,
                                               const float* __restrict__ W2,
                                               const float* __restrict__ b2,
                                               float* __restrict__ out) {
  int b = blockIdx.y, e = blockIdx.x, t = threadIdx.x;
  int wave = t >> 6, lane = t & 63;
  const float ks = 0.70710678118654752f;
  size_t po = ((size_t)b * E_ + e) * NHID_ + lane * 4;
  float4 p0 = *(const float4*)(ps + po);
  float4 p1 = *(const float4*)(ps + po + 256);
  float4 p2 = *(const float4*)(ps + po + 512);
  float4 p3 = *(const float4*)(ps + po + 768);
  const float* w2p = W2 + lane * 4;
  float4 w0 = *(const float4*)(w2p);
  float4 w1 = *(const float4*)(w2p + 256);
  float4 w2 = *(const float4*)(w2p + 512);
  float4 w3 = *(const float4*)(w2p + 768);
  __shared__ float outs[NA_];
#pragma unroll 2
  for (int a = wave; a < NA_; a += 4) {
    size_t qo = ((size_t)b * NA_ + a) * NHID_ + lane * 4;
    float4 q0 = *(const float4*)(qs + qo);
    float4 q1 = *(const float4*)(qs + qo + 256);
    float4 q2 = *(const float4*)(qs + qo + 512);
    float4 q3 = *(const float4*)(qs + qo + 768);
    float acc = 0.f;
#define GEL4(pp, qq, ww)                                          \
    {                                                             \
      float x0 = pp.x + qq.x, x1 = pp.y + qq.y;                   \
      float x2 = pp.z + qq.z, x3 = pp.w + qq.w;                   \
      float g0 = 0.5f * x0 * (1.f + erff(x0 * ks));               \
      float g1 = 0.5f * x1 * (1.f + erff(x1 * ks));               \
      float g2 = 0.5f * x2 * (1.f + erff(x2 * ks));               \
      float g3 = 0.5f * x3 * (1.f + erff(x3 * ks));               \
      acc += g0 * ww.x + g1 * ww.y + g2 * ww.z + g3 * ww.w;       \
    }
    GEL4(p0, q0, w0)
    GEL4(p1, q1, w1)
    GEL4(p2, q2, w2)
    GEL4(p3, q3, w3)
#undef GEL4
    acc += __shfl_xor(acc, 32);
    acc += __shfl_xor(acc, 16);
    acc += __shfl_xor(acc, 8);
    acc += __shfl_xor(acc, 4);
    acc += __shfl_xor(acc, 2);
    acc += __shfl_xor(acc, 1);
    if (lane == 0) outs[a] = acc;
  }
  __syncthreads();
  if (t < NA_) out[((size_t)b * E_ + e) * NA_ + t] = outs[t] + b2[0];
}

extern "C" void kernel_launch(void* const* d_in, const int* in_sizes, int n_in,
                              void* d_out, int out_size, void* d_ws, size_t ws_size,
                              hipStream_t stream) {
  const float* emb    = (const float*)d_in[0];
  const float* istrig = (const float*)d_in[1];
  const float* argw   = (const float*)d_in[2];
  const float* entmap = (const float*)d_in[3];
  const float* att0   = (const float*)d_in[4];
  const float* att1   = (const float*)d_in[5];
  const float* att2   = (const float*)d_in[6];
  const float* W_ta   = (const float*)d_in[7];
  const float* b_ta   = (const float*)d_in[8];
  const float* W1     = (const float*)d_in[9];
  const float* b1     = (const float*)d_in[10];
  const float* W2     = (const float*)d_in[11];
  const float* b2     = (const float*)d_in[12];
  const int*   idxs   = (const int*)d_in[13];
  const int*   blen   = (const int*)d_in[14];
  float* out = (float*)d_out;

  float* ws = (float*)d_ws;
  size_t o = 0;
  int* meta = (int*)ws; o += 256;
  float* sent_emb = ws + o; o += (size_t)B_ * S_ * D_;   // dead after phase A -> reused as ps
  float* arg_emb  = ws + o; o += (size_t)B_ * LA_ * D_;  // dead after argm  -> reused as qs
  float* trig     = ws + o; o += (size_t)B_ * D_;
  float* argm     = ws + o; o += (size_t)B_ * NA_ * D_;
  float* entn     = ws + o; o += (size_t)B_ * E_ * D_;
  float* tb       = ws + o; o += (size_t)B_ * D_;
  float* ne       = ws + o; o += (size_t)B_ * E_;
  float* score    = ws + o; o += (size_t)B_ * E_ * NA_;
  float* t2t      = ws + o; o += (size_t)B_ * S_ * S_;
  float* w2m      = ws + o; o += (size_t)B_ * E_ * S_;
  float* a2a      = ws + o; o += (size_t)B_ * NA_ * NA_;
  float* Cpe      = ws + o; o += (size_t)2 * 1024 * 768;
  float* PeAp     = ws + o; o += (size_t)2 * B_ * E_ * NHID_;
  float* PaAp     = ws + o; o += (size_t)2 * B_ * NA_ * NHID_;
  float* P2       = ws + o; o += (size_t)B_ * NA_ * NHID_;
  float* Q2       = ws + o; o += (size_t)B_ * E_ * NHID_;
  float* ps = sent_emb;  // 1.05M floats <= 1.23M
  float* qs = arg_emb;   // 0.52M floats <= 0.59M

  // split-bf16 region (hi/lo pairs), 16B-aligned
  o = (o + 3) & ~(size_t)3;
  unsigned short* us = (unsigned short*)(ws + o);
  size_t uo = 0;
  unsigned short* e0h   = us + uo; uo += (size_t)B_ * E_ * D_;
  unsigned short* e0l   = us + uo; uo += (size_t)B_ * E_ * D_;
  unsigned short* e0th  = us + uo; uo += (size_t)B_ * E_ * D_;
  unsigned short* e0tl  = us + uo; uo += (size_t)B_ * E_ * D_;
  unsigned short* Ah2hh = us + uo; uo += (size_t)B_ * E_ * D_;
  unsigned short* Ah2hl = us + uo; uo += (size_t)B_ * E_ * D_;
  unsigned short* argmh = us + uo; uo += (size_t)B_ * NA_ * D_;
  unsigned short* argml = us + uo; uo += (size_t)B_ * NA_ * D_;
  unsigned short* Au2uh = us + uo; uo += (size_t)B_ * NA_ * D_;
  unsigned short* Au2ul = us + uo; uo += (size_t)B_ * NA_ * D_;
  unsigned short* entnh = us + uo; uo += (size_t)B_ * E_ * D_;
  unsigned short* entnl = us + uo; uo += (size_t)B_ * E_ * D_;
  unsigned short* WtaTh = us + uo; uo += (size_t)2304 * 768;
  unsigned short* WtaTl = us + uo; uo += (size_t)2304 * 768;
  unsigned short* W1Th  = us + uo; uo += (size_t)4608 * 1024;
  unsigned short* W1Tl  = us + uo; uo += (size_t)4608 * 1024;

  // ---- phase A: gathers + weight transpose/split + everything not needing entity_new ----
  k_meta<<<B_, 128, 0, stream>>>(idxs, blen, meta);
  k_cvtT<<<dim3(2304 / 32, 768 / 32), 256, 0, stream>>>(W_ta, 2304, 768, WtaTh, WtaTl);
  k_cvtT<<<dim3(4608 / 32, 1024 / 32), 256, 0, stream>>>(W1, 4608, 1024, W1Th, W1Tl);
  k_gather<<<dim3(S_ + LA_, B_), 256, 0, stream>>>(emb, idxs, meta, sent_emb, arg_emb);
  k_trig<<<dim3(3, B_), 256, 0, stream>>>(sent_emb, istrig, trig);
  k_entity0<<<dim3(E_ * B_), 256, 0, stream>>>(sent_emb, entmap, trig, e0h, e0l, e0th,
                                               e0tl, ne);
  k_wsum<<<dim3(NA_ * B_), 256, 0, stream>>>(argw, LA_ * NA_, NA_, 1, arg_emb, argm, argmh,
                                             argml, LA_, NA_);
  k_tb<<<dim3(3, B_), 256, 0, stream>>>(trig, W_ta, b_ta, tb);
  k_t2t<<<dim3(S_, B_), 128, 0, stream>>>(att0, att1, att2, idxs, meta, t2t);
  k_eS<<<dim3(E_ * B_), 128, 0, stream>>>(entmap, t2t, w2m);
  k_wsum<<<dim3(E_ * B_), 256, 0, stream>>>(w2m, E_ * S_, 1, S_, sent_emb, nullptr, Ah2hh,
                                            Ah2hl, S_, E_);
  k_a2a<<<dim3(NA_ * B_), 256, 0, stream>>>(argm, a2a);
  k_wsum<<<dim3(NA_ * B_), 256, 0, stream>>>(a2a, NA_ * NA_, 1, NA_, argm, nullptr, Au2uh,
                                             Au2ul, NA_, NA_);

  // ---- phase B: XCD-pinned columns (160 gc = 1280 blocks) ----
  k_mgemm<<<dim3(1280), 256, 0, stream>>>(0, e0h, e0l, e0th, e0tl, Ah2hh, Ah2hl, argmh,
                                          argml, Au2uh, Au2ul, entnh, entnl, WtaTh, WtaTl,
                                          W1Th, W1Tl, Cpe, PeAp, PaAp, P2, Q2);

  // ---- combine entn halves + epilogue (tb, ne) + bf16 split ----
  k_combE<<<dim3(B_ * E_ / 4), 256, 0, stream>>>(Cpe, tb, ne, entn, entnh, entnl);

  // ---- Q2 = entn@W1[4] ----
  k_mgemm<<<dim3(256), 256, 0, stream>>>(1, e0h, e0l, e0th, e0tl, Ah2hh, Ah2hl, argmh,
                                         argml, Au2uh, Au2ul, entnh, entnl, WtaTh, WtaTl,
                                         W1Th, W1Tl, Cpe, PeAp, PaAp, P2, Q2);

  // ---- phase C: score, then mix (L1-norm fused) ----
  k_score<<<dim3(E_ * B_), 256, 0, stream>>>(entn, argm, score);
  k_mix<<<dim3(E_ + NA_, B_), 256, 0, stream>>>(PeAp, PaAp, P2, Q2, score, b1, ps, qs);

  // ---- final ----
  k_final<<<dim3(E_, B_), 256, 0, stream>>>(ps, qs, W2, b2, out);
}